// Round 1
// 235.881 us; speedup vs baseline: 1.0457x; 1.0457x over previous
//
#include <hip/hip_runtime.h>

#define BATCH 2048
#define SIZE 4096
#define DOWN 256
#define NTASK 16
#define KC 16
#define KCHUNK (SIZE / KC)  // 256

typedef _Float16 half8 __attribute__((ext_vector_type(8)));
typedef float floatx4 __attribute__((ext_vector_type(4)));

__device__ __forceinline__ int imin(int a, int b) { return a < b ? a : b; }
// 16B-granular XOR swizzle: spreads bank groups for b128 LDS writes/reads
__device__ __forceinline__ int uswz(int n) { return n ^ ((n >> 3) & 7); }

// ---------------- counting sort: group samples by task ----------------
__global__ __launch_bounds__(256) void sort_kernel(const int* __restrict__ task_id,
                                                   int* __restrict__ taskOff,
                                                   int* __restrict__ sortedIdx,
                                                   int* __restrict__ taskOfPos) {
    __shared__ int cnt[NTASK];
    __shared__ int base[NTASK + 1];
    __shared__ int cur[NTASK];
    int tid = threadIdx.x;
    if (tid < NTASK) cnt[tid] = 0;
    __syncthreads();
    for (int i = tid; i < BATCH; i += 256) atomicAdd(&cnt[task_id[i]], 1);
    __syncthreads();
    if (tid == 0) {
        int s = 0;
        for (int t = 0; t < NTASK; t++) { base[t] = s; s += cnt[t]; }
        base[NTASK] = s;
    }
    __syncthreads();
    if (tid < NTASK) { cur[tid] = base[tid]; taskOff[tid] = base[tid]; }
    if (tid == 0) taskOff[NTASK] = BATCH;
    __syncthreads();
    for (int i = tid; i < BATCH; i += 256) {
        int t = task_id[i];
        int p = atomicAdd(&cur[t], 1);
        sortedIdx[p] = i;
        taskOfPos[p] = t;
    }
}

// ---------------- GEMM1: partial[kc][s][h] = x[rows(t)] @ Wd[t] (K-chunked) ----
// grid (NTASK*2, KC): x = task*2 + z (row split). block 256 thr, tile M=64 x N=256,
// wave n-strip 64, BK=64. B staged via coalesced float4 preload + swizzled LDS.
__global__ __launch_bounds__(256, 2) void gemm1_kernel(const float* __restrict__ x,
                                                       const float* __restrict__ Wd,
                                                       const int* __restrict__ taskOff,
                                                       const int* __restrict__ sortedIdx,
                                                       _Float16* __restrict__ partial) {
    int task = blockIdx.x >> 1, z = blockIdx.x & 1, kc = blockIdx.y;
    int rowStart = taskOff[task];
    int nrows = taskOff[task + 1] - rowStart;
    if (nrows <= 0) return;

    __shared__ half8 A_lds[8][65];    // [kgroup][row], k-pack-8 (+1 pad)
    __shared__ half8 B_lds[8][256];   // [kgroup][swizzled n]

    int tid = threadIdx.x;
    int wave = tid >> 6, lane = tid & 63, quad = lane >> 4, l15 = lane & 15;
    int kbase0 = kc * KCHUNK;
    const float* Wdt = Wd + (size_t)task * SIZE * DOWN;

    // precomputed swizzled B-fragment read offsets (n = wave*64 + i*16 + l15)
    int bswz[4];
#pragma unroll
    for (int i = 0; i < 4; i++) bswz[i] = uswz(wave * 64 + i * 16 + l15);

    for (int r0 = z * 64; r0 < nrows; r0 += 128) {
        floatx4 acc[4][4];
#pragma unroll
        for (int mi = 0; mi < 4; mi++)
#pragma unroll
            for (int ni = 0; ni < 4; ni++) acc[mi][ni] = (floatx4){0.f, 0.f, 0.f, 0.f};

        int arow = tid >> 2;  // 0..63
        int asrc = sortedIdx[rowStart + imin(r0 + arow, nrows - 1)];
        const float* xrow = x + (size_t)asrc * SIZE;

        for (int kb = 0; kb < KCHUNK; kb += 64) {
            int kglob = kbase0 + kb;
            // ---- issue ALL global loads into registers (before barrier) ----
            floatx4 fa[2][2];
#pragma unroll
            for (int j = 0; j < 2; j++) {
                int kg = ((tid & 3) << 1) | j;
                const float* src = xrow + kglob + kg * 8;
                fa[j][0] = *(const floatx4*)(src);
                fa[j][1] = *(const floatx4*)(src + 4);
            }
            // B: thread owns 8k x 4n for kg = s*4 + wave; per-instr the wave reads
            // a contiguous 1KB slice of a Wd row (fully coalesced 16B/lane)
            floatx4 fb[2][8];
#pragma unroll
            for (int s = 0; s < 2; s++) {
                int kg = s * 4 + wave;
                const float* src = Wdt + (size_t)(kglob + kg * 8) * DOWN + lane * 4;
#pragma unroll
                for (int j = 0; j < 8; j++) fb[s][j] = *(const floatx4*)(src + (size_t)j * DOWN);
            }
            __syncthreads();  // previous compute phase done reading LDS
            // ---- convert + stage to LDS ----
#pragma unroll
            for (int j = 0; j < 2; j++) {
                int kg = ((tid & 3) << 1) | j;
                half8 h;
                h[0] = (_Float16)fa[j][0][0]; h[1] = (_Float16)fa[j][0][1];
                h[2] = (_Float16)fa[j][0][2]; h[3] = (_Float16)fa[j][0][3];
                h[4] = (_Float16)fa[j][1][0]; h[5] = (_Float16)fa[j][1][1];
                h[6] = (_Float16)fa[j][1][2]; h[7] = (_Float16)fa[j][1][3];
                A_lds[kg][arow] = h;
            }
#pragma unroll
            for (int s = 0; s < 2; s++) {
                int kg = s * 4 + wave;
#pragma unroll
                for (int i = 0; i < 4; i++) {
                    half8 h;
#pragma unroll
                    for (int j = 0; j < 8; j++) h[j] = (_Float16)fb[s][j][i];
                    B_lds[kg][uswz(lane * 4 + i)] = h;
                }
            }
            __syncthreads();
            // ---- MFMA ----
#pragma unroll
            for (int ks = 0; ks < 2; ks++) {
                int kg = ks * 4 + quad;
                half8 a[4], b[4];
#pragma unroll
                for (int i = 0; i < 4; i++) a[i] = A_lds[kg][i * 16 + l15];
#pragma unroll
                for (int i = 0; i < 4; i++) b[i] = B_lds[kg][bswz[i]];
#pragma unroll
                for (int mi = 0; mi < 4; mi++)
#pragma unroll
                    for (int ni = 0; ni < 4; ni++)
                        acc[mi][ni] = __builtin_amdgcn_mfma_f32_16x16x32_f16(
                            a[mi], b[ni], acc[mi][ni], 0, 0, 0);
            }
        }
        // epilogue: partial[kc][rowStart+r][h], fp16
#pragma unroll
        for (int mi = 0; mi < 4; mi++) {
#pragma unroll
            for (int reg = 0; reg < 4; reg++) {
                int r = r0 + mi * 16 + quad * 4 + reg;
                if (r < nrows) {
                    size_t rowoff = ((size_t)kc * BATCH + (rowStart + r)) * DOWN;
#pragma unroll
                    for (int ni = 0; ni < 4; ni++) {
                        int h = wave * 64 + ni * 16 + l15;
                        partial[rowoff + h] = (_Float16)acc[mi][ni][reg];
                    }
                }
            }
        }
    }
}

// ---------------- SiLU: act[s][h] = silu(sum_kc partial + bd), half8-vectorized --
__global__ __launch_bounds__(256) void silu_kernel(const _Float16* __restrict__ partial,
                                                   const float* __restrict__ bd,
                                                   const int* __restrict__ taskOfPos,
                                                   _Float16* __restrict__ act) {
    int idx = blockIdx.x * 256 + threadIdx.x;  // BATCH*DOWN/8 = 65536 total
    int s = idx >> 5;            // 32 half8 chunks per row
    int h = (idx & 31) * 8;
    int t = taskOfPos[s];
    floatx4 b0 = *(const floatx4*)(bd + t * DOWN + h);
    floatx4 b1 = *(const floatx4*)(bd + t * DOWN + h + 4);
    float v[8];
    v[0] = b0[0]; v[1] = b0[1]; v[2] = b0[2]; v[3] = b0[3];
    v[4] = b1[0]; v[5] = b1[1]; v[6] = b1[2]; v[7] = b1[3];
#pragma unroll
    for (int kc = 0; kc < KC; kc++) {
        half8 p = *(const half8*)(partial + ((size_t)kc * BATCH + s) * DOWN + h);
#pragma unroll
        for (int j = 0; j < 8; j++) v[j] += (float)p[j];
    }
    half8 o;
#pragma unroll
    for (int j = 0; j < 8; j++) {
        float sv = v[j] / (1.0f + __expf(-v[j]));
        o[j] = (_Float16)sv;
    }
    *(half8*)(act + (size_t)s * DOWN + h) = o;
}

// ---------------- GEMM2: out = x + act @ Wu[t] + bu ----------------
// grid (SIZE/128, NTASK): x = n-tile (fastest, spreads act reuse). block 256 thr,
// tile M=128 x N=128, waves 2x2, K=256, BK=64. Same staging scheme as GEMM1.
__global__ __launch_bounds__(256, 2) void gemm2_kernel(const _Float16* __restrict__ act,
                                                       const float* __restrict__ Wu,
                                                       const float* __restrict__ bu,
                                                       const float* __restrict__ x,
                                                       const int* __restrict__ taskOff,
                                                       const int* __restrict__ sortedIdx,
                                                       float* __restrict__ out) {
    int nt = blockIdx.x, task = blockIdx.y;
    int rowStart = taskOff[task];
    int nrows = taskOff[task + 1] - rowStart;
    if (nrows <= 0) return;

    __shared__ half8 A_lds[8][129];  // [kgroup][row 0..127] (+1 pad)
    __shared__ half8 B_lds[8][128];  // [kgroup][swizzled n]

    int tid = threadIdx.x;
    int wave = tid >> 6, lane = tid & 63, quad = lane >> 4, l15 = lane & 15;
    int wm = wave >> 1, wn = wave & 1;
    int ncol0 = nt * 128;
    const float* Wut = Wu + (size_t)task * DOWN * SIZE;

    int bswz[4];
#pragma unroll
    for (int i = 0; i < 4; i++) bswz[i] = uswz(wn * 64 + i * 16 + l15);
    int kgB = tid >> 5, nfB = tid & 31;  // B-staging ownership: 8k x 4n per thread

    for (int r0 = 0; r0 < nrows; r0 += 128) {
        floatx4 acc[4][4];
#pragma unroll
        for (int mi = 0; mi < 4; mi++)
#pragma unroll
            for (int ni = 0; ni < 4; ni++) acc[mi][ni] = (floatx4){0.f, 0.f, 0.f, 0.f};

        int arow = tid >> 1;  // 0..127
        int s_a = rowStart + imin(r0 + arow, nrows - 1);
        const _Float16* actrow = act + (size_t)s_a * DOWN;

        for (int kb = 0; kb < DOWN; kb += 64) {
            // ---- issue ALL global loads into registers ----
            half8 ha[4];
#pragma unroll
            for (int j = 0; j < 4; j++) {
                int kg = ((tid & 1) << 2) | j;
                ha[j] = *(const half8*)(actrow + kb + kg * 8);
            }
            floatx4 fb[8];
            const float* src = Wut + (size_t)(kb + kgB * 8) * SIZE + ncol0 + nfB * 4;
#pragma unroll
            for (int j = 0; j < 8; j++) fb[j] = *(const floatx4*)(src + (size_t)j * SIZE);
            __syncthreads();
            // ---- stage to LDS ----
#pragma unroll
            for (int j = 0; j < 4; j++) {
                int kg = ((tid & 1) << 2) | j;
                A_lds[kg][arow] = ha[j];
            }
#pragma unroll
            for (int i = 0; i < 4; i++) {
                half8 h;
#pragma unroll
                for (int j = 0; j < 8; j++) h[j] = (_Float16)fb[j][i];
                B_lds[kgB][uswz(nfB * 4 + i)] = h;
            }
            __syncthreads();
            // ---- MFMA ----
#pragma unroll
            for (int ks = 0; ks < 2; ks++) {
                int kg = ks * 4 + quad;
                half8 a[4], b[4];
#pragma unroll
                for (int i = 0; i < 4; i++) a[i] = A_lds[kg][wm * 64 + i * 16 + l15];
#pragma unroll
                for (int i = 0; i < 4; i++) b[i] = B_lds[kg][bswz[i]];
#pragma unroll
                for (int mi = 0; mi < 4; mi++)
#pragma unroll
                    for (int ni = 0; ni < 4; ni++)
                        acc[mi][ni] = __builtin_amdgcn_mfma_f32_16x16x32_f16(
                            a[mi], b[ni], acc[mi][ni], 0, 0, 0);
            }
        }
        // epilogue: scatter to original rows, add bias + fp32 residual
#pragma unroll
        for (int mi = 0; mi < 4; mi++) {
#pragma unroll
            for (int reg = 0; reg < 4; reg++) {
                int r = r0 + wm * 64 + mi * 16 + quad * 4 + reg;
                if (r < nrows) {
                    int b = sortedIdx[rowStart + r];
                    const float* xr = x + (size_t)b * SIZE;
                    float* outr = out + (size_t)b * SIZE;
#pragma unroll
                    for (int ni = 0; ni < 4; ni++) {
                        int n = ncol0 + wn * 64 + ni * 16 + l15;
                        outr[n] = acc[mi][ni][reg] + bu[task * SIZE + n] + xr[n];
                    }
                }
            }
        }
    }
}

extern "C" void kernel_launch(void* const* d_in, const int* in_sizes, int n_in,
                              void* d_out, int out_size, void* d_ws, size_t ws_size,
                              hipStream_t stream) {
    const float* x       = (const float*)d_in[0];
    const int*   task_id = (const int*)d_in[1];
    const float* Wd      = (const float*)d_in[2];
    const float* bd      = (const float*)d_in[3];
    const float* Wu      = (const float*)d_in[4];
    const float* bu      = (const float*)d_in[5];
    float* out = (float*)d_out;

    // partial (16 MB) lives in d_out: it is dead before gemm2 launches, and
    // gemm2 overwrites every byte of d_out. act + index arrays live in d_ws.
    _Float16* partial = (_Float16*)d_out;               // KC*BATCH*DOWN fp16 = 16 MB (of 32 MB)
    _Float16* act     = (_Float16*)d_ws;                // BATCH*DOWN fp16 = 1 MB
    int* taskOff   = (int*)(act + (size_t)BATCH * DOWN);
    int* sortedIdx = taskOff + 32;
    int* taskOfPos = sortedIdx + BATCH;

    sort_kernel<<<1, 256, 0, stream>>>(task_id, taskOff, sortedIdx, taskOfPos);
    gemm1_kernel<<<dim3(NTASK * 2, KC), 256, 0, stream>>>(x, Wd, taskOff, sortedIdx, partial);
    silu_kernel<<<(BATCH * DOWN / 8) / 256, 256, 0, stream>>>(partial, bd, taskOfPos, act);
    gemm2_kernel<<<dim3(SIZE / 128, NTASK), 256, 0, stream>>>(act, Wu, bu, x, taskOff,
                                                              sortedIdx, out);
}